// Round 13
// baseline (26417.126 us; speedup 1.0000x reference)
//
#include <hip/hip_runtime.h>
#include <stdint.h>

#define NTOT    131072
#define NSTEP   60
#define NBLK    (NTOT / 128)   // 1024 blocks: 4 waves x 32 samples, wave-complete
#define PLANE_H 16384          // halves per A-image plane (128x128 frag order)
#define IMG_H   32768          // halves per A image (hi + lo plane)

// dynamic LDS: per-wave private ACT quadrants + params. NO D storage in LDS —
// D2/D3 live in fp32 registers (launch_bounds(256,1) -> ~256-reg budget).
// f16/bf16 D is FORBIDDEN: 60-step clipped-Langevin chaos amplifies ~1e4x;
// 2^-11 D error saturates clip bounds (r7/r8/r11: absmax 5.484 = clip span).
#define OFF_ACT  0             // 4 x 16384 = 65536 B
#define OFF_W1C  65536         // 2048 B
#define OFF_B2   67584         // 512 B
#define OFF_B3   68096
#define OFF_B4   68608
#define OFF_W5   69120
#define LDS_TOTAL 69632

typedef float  f32x4  __attribute__((ext_vector_type(4)));
typedef float  f32x16 __attribute__((ext_vector_type(16)));
typedef short  bf16x8 __attribute__((ext_vector_type(8)));
union FragU { bf16x8 v; uint32_t u[4]; uint16_t h[8]; };

static __device__ __forceinline__ uint32_t rne_bits(float f) {
  uint32_t u = __float_as_uint(f);
  return u + 0x7fffu + ((u >> 16) & 1u);   // high16 = rne bf16
}
static __device__ __forceinline__ float fsigm(float z) {
  return __builtin_amdgcn_rcpf(1.0f + __builtin_amdgcn_exp2f(z * -1.44269504089f));
}
static __device__ __forceinline__ uint32_t cvt_pk_bf16(float a, float b) {
  uint32_t r;
  asm("v_cvt_pk_bf16_f32 %0, %1, %2" : "=v"(r) : "v"(a), "v"(b));
  return r;
}

// ---- prep: 6 fragment-order (32x32x16 A-layout) split-bf16 W images ----
// img 0..2: forward A = W^T of w2,w3,w4 (m=out, k=in)
// img 3..5: backward A = W natural of w4,w3,w2 (m=in, k=out)
extern "C" __global__ void ebm_prep_kernel(const float* __restrict__ w2,
                                           const float* __restrict__ w3,
                                           const float* __restrict__ w4,
                                           uint16_t* __restrict__ ws) {
  int img = blockIdx.x;
  bool bwd = img >= 3;
  int li = bwd ? 5 - img : img;
  const float* w = (li == 0) ? w2 : (li == 1) ? w3 : w4;
  uint16_t* hiP = ws + (size_t)img * IMG_H;
  uint16_t* loP = hiP + PLANE_H;
  for (int e = threadIdx.x; e < 16384; e += blockDim.x) {
    int i = e >> 7, o = e & 127;            // w[i][o]
    int m = bwd ? i : o;
    int k = bwd ? o : i;
    int slot = ((m >> 5) * 8 + (k >> 4)) * 64 + (m & 31) + 32 * ((k >> 3) & 1);
    int off = slot * 8 + (k & 7);
    float v = w[e];
    uint32_t tb = rne_bits(v);
    float lo = v - __uint_as_float(tb & 0xffff0000u);
    hiP[off] = (uint16_t)(tb >> 16);
    loP[off] = (uint16_t)(rne_bits(lo) >> 16);
  }
}

// Wave-complete MCMC: each wave owns 32 samples end-to-end (all 128 hidden
// dims, acc[4]); layer-to-layer relayout via the wave's PRIVATE LDS quadrant
// using the r5-verified storeAct/B-read formula pair. Same-wave DS ops are
// in-order -> single buffer, ZERO __syncthreads in the step loop.
extern "C" __global__ void __launch_bounds__(256, 1)
ebm_mcmc_kernel(const float* __restrict__ x0, const float* __restrict__ w1,
                const float* __restrict__ b1, const float* __restrict__ b2,
                const float* __restrict__ b3, const float* __restrict__ b4,
                const float* __restrict__ w5, const float* __restrict__ noise,
                const uint16_t* __restrict__ wsW, float* __restrict__ out)
{
  extern __shared__ char smem[];
  f32x4* W1C = (f32x4*)(smem + OFF_W1C);   // (w1[0][n], w1[1][n], b1[n], 0)
  float* B2s = (float*)(smem + OFF_B2);
  float* B3s = (float*)(smem + OFF_B3);
  float* B4s = (float*)(smem + OFF_B4);
  float* W5s = (float*)(smem + OFF_W5);

  const int t   = threadIdx.x;
  const int blk = blockIdx.x;

  if (t < 128) {
    f32x4 v; v.x = w1[t]; v.y = w1[128 + t]; v.z = b1[t]; v.w = 0.0f;
    W1C[t] = v;
    B2s[t] = b2[t]; B3s[t] = b3[t]; B4s[t] = b4[t]; W5s[t] = w5[t];
  }

  const int lane = t & 63;
  const int wave = t >> 6;
  const int n    = lane & 31;     // sample within wave tile (MFMA col)
  const int h    = lane >> 5;     // lane half
  uint16_t* ACTW = (uint16_t*)(smem + OFF_ACT) + wave * 8192;  // private quadrant

  const int gs = blk * 128 + wave * 32 + n;   // global sample
  const float2* x02 = (const float2*)x0;
  const float2* nz2 = (const float2*)noise;
  float2* out2 = (float2*)out;

  float2 x  = x02[gs];
  float2 nz = nz2[gs];            // step-0 noise

  __syncthreads();                // params ready; the ONLY barrier

  f32x16 acc[4];                  // 4 row-tiles of 32x32 C per wave
  float D2[64], D3[64];           // fp32 silu' in REGISTERS [rt*16 + 4*tt + rr]

  // value (rt, tt, rr) = row k = 32rt + 8tt + 4h + rr, col n (r5-verified pair)
  auto storeAct = [&](int rt, int tt, f32x4 v) {
    uint32_t h01 = cvt_pk_bf16(v[0], v[1]);
    uint32_t h23 = cvt_pk_bf16(v[2], v[3]);
    float r0 = v[0] - __uint_as_float(h01 << 16);
    float r1 = v[1] - __uint_as_float(h01 & 0xffff0000u);
    float r2 = v[2] - __uint_as_float(h23 << 16);
    float r3 = v[3] - __uint_as_float(h23 & 0xffff0000u);
    int slot = (2 * rt + (tt >> 1)) * 64 + n + 32 * (tt & 1);
    uint16_t* p = ACTW + slot * 8 + 4 * h;
    *(uint2*)p = make_uint2(h01, h23);
    *(uint2*)(p + 4096) = make_uint2(cvt_pk_bf16(r0, r1), cvt_pk_bf16(r2, r3));
  };

  // A streams from L2 (6 frag-order images, 384 KB, L2-resident; 4 waves share
  // via L1). B from the private quadrant. 4 independent acc chains (ILP).
  auto gemm = [&](int img) {
    const uint16_t* ab = wsW + (size_t)img * IMG_H + (size_t)lane * 8;
#pragma unroll
    for (int rt = 0; rt < 4; ++rt) acc[rt] = (f32x16)0.0f;
#pragma unroll
    for (int ks = 0; ks < 8; ++ks) {
      FragU Bh, Bl;
      const uint16_t* bp = ACTW + (ks * 64 + lane) * 8;
      Bh.v = *(const bf16x8*)bp;
      Bl.v = *(const bf16x8*)(bp + 4096);
#pragma unroll
      for (int rt = 0; rt < 4; ++rt) {
        FragU Ah, Al;
        Ah.v = *(const bf16x8*)(ab + (rt * 8 + ks) * 512);
        Al.v = *(const bf16x8*)(ab + (rt * 8 + ks) * 512 + PLANE_H);
        acc[rt] = __builtin_amdgcn_mfma_f32_32x32x16_bf16(Ah.v, Bh.v, acc[rt], 0, 0, 0);
        acc[rt] = __builtin_amdgcn_mfma_f32_32x32x16_bf16(Ah.v, Bl.v, acc[rt], 0, 0, 0);
        acc[rt] = __builtin_amdgcn_mfma_f32_32x32x16_bf16(Al.v, Bh.v, acc[rt], 0, 0, 0);
      }
    }
  };

  auto l1_phase = [&]() {
#pragma unroll
    for (int rt = 0; rt < 4; ++rt)
#pragma unroll
      for (int tt = 0; tt < 4; ++tt) {
        const f32x4* wp = &W1C[32 * rt + 8 * tt + 4 * h];
        f32x4 hv;
#pragma unroll
        for (int rr = 0; rr < 4; ++rr) {
          f32x4 w = wp[rr];
          float z = fmaf(x.x, w.x, fmaf(x.y, w.y, w.z));
          float s = fsigm(z);
          hv[rr] = z * s;                    // D1 recomputed later (r9-verified)
        }
        storeAct(rt, tt, hv);
      }
  };

  auto ep_fwd = [&](const float* Bs, float* D) {
#pragma unroll
    for (int rt = 0; rt < 4; ++rt)
#pragma unroll
      for (int tt = 0; tt < 4; ++tt) {
        f32x4 bv = *(const f32x4*)(Bs + 32 * rt + 8 * tt + 4 * h);
        f32x4 hv;
#pragma unroll
        for (int rr = 0; rr < 4; ++rr) {
          float z = acc[rt][4 * tt + rr] + bv[rr];
          float s = fsigm(z);
          float hh = z * s;
          D[rt * 16 + 4 * tt + rr] = s * (1.0f + z - hh);   // fp32 register
          hv[rr] = hh;
        }
        storeAct(rt, tt, hv);
      }
  };

  auto ep_v4 = [&]() {
#pragma unroll
    for (int rt = 0; rt < 4; ++rt)
#pragma unroll
      for (int tt = 0; tt < 4; ++tt) {
        f32x4 bv = *(const f32x4*)(B4s + 32 * rt + 8 * tt + 4 * h);
        f32x4 wv = *(const f32x4*)(W5s + 32 * rt + 8 * tt + 4 * h);
        f32x4 vv;
#pragma unroll
        for (int rr = 0; rr < 4; ++rr) {
          float z = acc[rt][4 * tt + rr] + bv[rr];
          float s = fsigm(z);
          vv[rr] = wv[rr] * (s * (1.0f + z - z * s));
        }
        storeAct(rt, tt, vv);
      }
  };

  auto ep_bwd = [&](const float* D) {
#pragma unroll
    for (int rt = 0; rt < 4; ++rt)
#pragma unroll
      for (int tt = 0; tt < 4; ++tt) {
        f32x4 vv;
#pragma unroll
        for (int rr = 0; rr < 4; ++rr)
          vv[rr] = acc[rt][4 * tt + rr] * D[rt * 16 + 4 * tt + rr];
        storeAct(rt, tt, vv);
      }
  };

  // u1 epilogue + Langevin update: D1 recomputed from pre-update x
  // (r9-verified); lanes (n,0)/(n,1) cover all 128 rows -> one shfl_xor(32).
  auto ep_bwd1_update = [&](int step) {
    float gx = 0.f, gy = 0.f;
#pragma unroll
    for (int rt = 0; rt < 4; ++rt)
#pragma unroll
      for (int tt = 0; tt < 4; ++tt) {
        const f32x4* wp = &W1C[32 * rt + 8 * tt + 4 * h];
#pragma unroll
        for (int rr = 0; rr < 4; ++rr) {
          f32x4 w = wp[rr];
          float z = fmaf(x.x, w.x, fmaf(x.y, w.y, w.z));
          float s = fsigm(z);
          float hh = z * s;
          float d1 = s * (1.0f + z - hh);
          float v = acc[rt][4 * tt + rr] * d1;
          gx = fmaf(v, w.x, gx);
          gy = fmaf(v, w.y, gy);
        }
      }
    gx += __shfl_xor(gx, 32);
    gy += __shfl_xor(gy, 32);
    float gxc = fminf(fmaxf(gx, -0.03f), 0.03f);
    float gyc = fminf(fmaxf(gy, -0.03f), 0.03f);
    float epsv = 10.0f * (1.0f - (float)step / 60.0f);
    float sq = sqrtf(2.0f * epsv);
    x.x = fminf(fmaxf(x.x + sq * nz.x * 0.005f + epsv * gxc, -2.43f), 3.05f);
    x.y = fminf(fmaxf(x.y + sq * nz.y * 0.005f + epsv * gyc, -2.43f), 3.05f);
    if (step == NSTEP - 1) {
      if (h == 0) out2[gs] = x;
    } else {
      nz = nz2[(size_t)(step + 1) * NTOT + gs];
    }
  };

#pragma unroll 1
  for (int step = 0; step < NSTEP; ++step) {
    l1_phase();
    gemm(0); ep_fwd(B2s, D2);      // z2 (A = W2^T)
    gemm(1); ep_fwd(B3s, D3);      // z3
    gemm(2); ep_v4();              // z4 -> v4
    gemm(3); ep_bwd(D3);           // u3 (A = W4 nat) -> v3
    gemm(4); ep_bwd(D2);           // u2 -> v2
    gemm(5); ep_bwd1_update(step); // u1 -> g -> x update
  }
}

extern "C" void kernel_launch(void* const* d_in, const int* in_sizes, int n_in,
                              void* d_out, int out_size, void* d_ws, size_t ws_size,
                              hipStream_t stream) {
  // inputs: x0,w1,b1,w2,b2,w3,b3,w4,b4,w5,b5,noise
  (void)in_sizes; (void)n_in; (void)out_size; (void)ws_size;
  hipFuncSetAttribute((const void*)ebm_mcmc_kernel,
                      hipFuncAttributeMaxDynamicSharedMemorySize, LDS_TOTAL);
  ebm_prep_kernel<<<6, 256, 0, stream>>>(
      (const float*)d_in[3], (const float*)d_in[5], (const float*)d_in[7],
      (uint16_t*)d_ws);
  ebm_mcmc_kernel<<<NBLK, 256, LDS_TOTAL, stream>>>(
      (const float*)d_in[0], (const float*)d_in[1], (const float*)d_in[2],
      (const float*)d_in[4], (const float*)d_in[6], (const float*)d_in[8],
      (const float*)d_in[9], (const float*)d_in[11], (const uint16_t*)d_ws,
      (float*)d_out);
}